// Round 1
// 483.992 us; speedup vs baseline: 1.4970x; 1.4970x over previous
//
#include <hip/hip_runtime.h>
#include <cstddef>

// Problem constants: B=4, S=2048, D=1024, H=16, HD=64
constexpr int Bn  = 4;
constexpr int Sn  = 2048;
constexpr int Dn  = 1024;
constexpr int Hn  = 16;
constexpr int HDn = 64;

typedef __bf16 bf16;
typedef __attribute__((ext_vector_type(8))) __bf16 bf16x8;
typedef __attribute__((ext_vector_type(4))) __bf16 bf16x4;
typedef __attribute__((ext_vector_type(4))) float  f32x4;

// ---------------------------------------------------------------------------
// Elementwise fp32 -> bf16 (x staging)
// ---------------------------------------------------------------------------
__global__ __launch_bounds__(256) void conv_f32_bf16_k(
    const float* __restrict__ in, bf16* __restrict__ out, int n)
{
    int i = (blockIdx.x * 256 + threadIdx.x) * 4;
    if (i + 3 < n) {
        float4 v = *(const float4*)(in + i);
        bf16 o[4] = {(bf16)v.x, (bf16)v.y, (bf16)v.z, (bf16)v.w};
        *(ulong1*)(out + i) = *(ulong1*)o;  // 8B store
    }
}

// ---------------------------------------------------------------------------
// Weight transpose + convert: W[k][n] fp32 -> Wt[n][k] bf16. 64x64 tiles.
// blockIdx.z selects which of the 4 weight matrices.
// ---------------------------------------------------------------------------
__global__ __launch_bounds__(256) void conv_wt_k(
    const float* __restrict__ w0, const float* __restrict__ w1,
    const float* __restrict__ w2, const float* __restrict__ w3,
    bf16* __restrict__ o0, bf16* __restrict__ o1,
    bf16* __restrict__ o2, bf16* __restrict__ o3)
{
    const float* W = (blockIdx.z == 0) ? w0 : (blockIdx.z == 1) ? w1
                   : (blockIdx.z == 2) ? w2 : w3;
    bf16* O = (blockIdx.z == 0) ? o0 : (blockIdx.z == 1) ? o1
            : (blockIdx.z == 2) ? o2 : o3;
    __shared__ float t[64][65];
    const int tid = threadIdx.x;
    const int k0 = blockIdx.x * 64;   // row of W (k-dim)
    const int n0 = blockIdx.y * 64;   // col of W (n-dim)
    #pragma unroll
    for (int p = 0; p < 16; ++p) {
        const int idx = p * 256 + tid;
        const int r = idx >> 6, c = idx & 63;
        t[r][c] = W[(size_t)(k0 + r) * Dn + n0 + c];
    }
    __syncthreads();
    #pragma unroll
    for (int p = 0; p < 16; ++p) {
        const int idx = p * 256 + tid;
        const int r = idx >> 6, c = idx & 63;   // r: n-offset, c: k-offset
        O[(size_t)(n0 + r) * Dn + k0 + c] = (bf16)t[c][r];
    }
}

// ---------------------------------------------------------------------------
// bf16 MFMA GEMM: out = A(8192 x 1024) @ Bt^T + bias, Bt is [N][K] bf16.
// Block: 256 thr / 4 waves; tile 64x64, BK=64. Wave w owns rows w*16..w*16+15.
// MFMA 16x16x32 bf16; fragment maps (verified):
//   A[m=lane&15][k=(lane>>4)*8+j], B[k=(lane>>4)*8+j][n=lane&15],
//   C/D: col=lane&15, row=(lane>>4)*4+reg.
// MODE 0: fp32 out [M][N] (final projection)
// MODE 1: bf16 out [b,h,s,hd]  (Q, K)
// MODE 2: bf16 out [b,h,hd,s]  (V transposed for the PV B-operand)
// ---------------------------------------------------------------------------
template <int MODE>
__global__ __launch_bounds__(256) void gemm_bf16_k(
    const bf16* __restrict__ A, const bf16* __restrict__ Bt,
    const float* __restrict__ bias, void* __restrict__ outv)
{
    __shared__ __align__(16) bf16 As[64][72];
    __shared__ __align__(16) bf16 Bs[64][72];

    const int tid  = threadIdx.x;
    const int w    = tid >> 6;
    const int lane = tid & 63;
    const int quad = lane >> 4;
    const int l15  = lane & 15;
    const int m0   = blockIdx.x * 64;
    const int n0   = blockIdx.y * 64;

    f32x4 acc[4] = {};

    for (int k0 = 0; k0 < Dn; k0 += 64) {
        #pragma unroll
        for (int p = 0; p < 2; ++p) {
            const int c = p * 256 + tid;
            const int r = c >> 3, off = (c & 7) * 8;
            *(bf16x8*)&As[r][off] =
                *(const bf16x8*)(A + (size_t)(m0 + r) * Dn + k0 + off);
            *(bf16x8*)&Bs[r][off] =
                *(const bf16x8*)(Bt + (size_t)(n0 + r) * Dn + k0 + off);
        }
        __syncthreads();
        #pragma unroll
        for (int ks = 0; ks < 64; ks += 32) {
            bf16x8 af = *(const bf16x8*)&As[w * 16 + l15][ks + quad * 8];
            #pragma unroll
            for (int ct = 0; ct < 4; ++ct) {
                bf16x8 bfr = *(const bf16x8*)&Bs[ct * 16 + l15][ks + quad * 8];
                acc[ct] = __builtin_amdgcn_mfma_f32_16x16x32_bf16(af, bfr, acc[ct], 0, 0, 0);
            }
        }
        __syncthreads();
    }

    #pragma unroll
    for (int ct = 0; ct < 4; ++ct) {
        const int c = n0 + ct * 16 + l15;
        const float bv = bias[c];
        #pragma unroll
        for (int i = 0; i < 4; ++i) {
            const int m = m0 + w * 16 + quad * 4 + i;
            const float v = acc[ct][i] + bv;
            if (MODE == 0) {
                ((float*)outv)[(size_t)m * Dn + c] = v;
            } else {
                const int b = m >> 11, s = m & (Sn - 1);
                const int h = c >> 6, hd = c & 63;
                if (MODE == 1)
                    ((bf16*)outv)[(((size_t)(b * Hn + h) * Sn) + s) * HDn + hd] = (bf16)v;
                else
                    ((bf16*)outv)[(((size_t)(b * Hn + h) * HDn) + hd) * Sn + s] = (bf16)v;
            }
        }
    }
}

// ---------------------------------------------------------------------------
// Flash attention, bf16 MFMA, SWAPPED QK^T (S^T = K Q^T) so each lane owns a
// single q-row's energies in registers:
//   s = mfma(Kfrag, Qfrag): element (k = ct*16 + quad*4 + i, q = w*16 + l15).
// Softmax: 15 in-reg max/sum ops + 2 shfl_xor (cross-quad) per chunk; per-lane
// scalar running m/l in log2 domain (scale folds in log2(e)). P written to LDS
// in [q][k] layout via 4x ds_write_b64 (wave-local rows, no barrier), PV via
// MFMA exactly as before. Q held in 2 register fragments (no Qs LDS).
// alpha/l re-broadcast to the O-row layout (row = quad*4+i) via width-16 shfl.
// ---------------------------------------------------------------------------
__global__ __launch_bounds__(256) void attn_mfma_k(
    const bf16* __restrict__ Qb, const bf16* __restrict__ Kb,
    const bf16* __restrict__ Vtb, const int* __restrict__ kpm,
    const float* __restrict__ mod, bf16* __restrict__ att)
{
    __shared__ __align__(16) bf16 Ks[64][72];
    __shared__ __align__(16) bf16 Vts[64][72];
    __shared__ __align__(16) bf16 Ps[64][72];

    const int tid  = threadIdx.x;
    const int w    = tid >> 6;
    const int lane = tid & 63;
    const int quad = lane >> 4;
    const int l15  = lane & 15;
    const int bh   = blockIdx.x;
    const int b    = bh >> 4;
    const int h    = bh & 15;
    const int q0   = blockIdx.y * 64;
    const size_t base = (size_t)bh * Sn * HDn;

    const int qrow = q0 + w * 16 + l15;        // this lane's softmax q-row
    // Q fragments in registers: B-operand B[k][n=l15] = Q[qrow][k]
    const bf16x8 qf0 = *(const bf16x8*)(Qb + base + (size_t)qrow * HDn + 0  + quad * 8);
    const bf16x8 qf1 = *(const bf16x8*)(Qb + base + (size_t)qrow * HDn + 32 + quad * 8);

    const bool qm = kpm[(size_t)b * Sn + qrow] != 0;
    const float* modrow = mod + ((size_t)b * Sn + qrow) * Sn;

    // 1/sqrt(hd) * log2(e): softmax runs in log2 domain -> raw v_exp_f32
    constexpr float SC = 0.125f * 1.44269504088896340736f;

    float m_r = -1e30f;
    float l_r = 0.0f;
    f32x4 O[4] = {};

    for (int k0 = 0; k0 < Sn; k0 += 64) {
        // Stage K chunk [key][d] and Vt chunk [d][key].
        #pragma unroll
        for (int p = 0; p < 2; ++p) {
            const int c = p * 256 + tid;
            const int r = c >> 3, off = (c & 7) * 8;
            *(bf16x8*)&Ks[r][off] =
                *(const bf16x8*)(Kb + base + (size_t)(k0 + r) * HDn + off);
            *(bf16x8*)&Vts[r][off] =
                *(const bf16x8*)(Vtb + base + (size_t)r * Sn + k0 + off);
        }
        // mod tile: 4 coalesced float4 loads (k = k0+ct*16+quad*4 .. +3),
        // issued before the barrier so latency hides under staging+MFMA.
        float4 md[4];
        #pragma unroll
        for (int ct = 0; ct < 4; ++ct)
            md[ct] = *(const float4*)(modrow + k0 + ct * 16 + quad * 4);
        __syncthreads();

        // Swapped QK^T: lane holds e[k = ct*16+quad*4+i] for its own q-row.
        float e[4][4];
        #pragma unroll
        for (int ct = 0; ct < 4; ++ct) {
            f32x4 s = {};
            #pragma unroll
            for (int ks = 0; ks < 64; ks += 32) {
                bf16x8 kf = *(const bf16x8*)&Ks[ct * 16 + l15][ks + quad * 8];
                s = __builtin_amdgcn_mfma_f32_16x16x32_bf16(kf, ks ? qf1 : qf0, s, 0, 0, 0);
            }
            #pragma unroll
            for (int i = 0; i < 4; ++i)
                e[ct][i] = qm ? -1e10f : s[i] * SC * (&md[ct].x)[i];
        }

        // Row max: 15 in-reg fmax + 2 cross-quad shfl_xor.
        float pmax = e[0][0];
        #pragma unroll
        for (int ct = 0; ct < 4; ++ct)
            #pragma unroll
            for (int i = 0; i < 4; ++i)
                pmax = fmaxf(pmax, e[ct][i]);
        pmax = fmaxf(pmax, __shfl_xor(pmax, 16));
        pmax = fmaxf(pmax, __shfl_xor(pmax, 32));

        const float mnew  = fmaxf(m_r, pmax);
        const float alpha = __builtin_amdgcn_exp2f(m_r - mnew);
        m_r = mnew;

        // P = exp2(e - mnew), bf16-rounded; store [q][k] via ds_write_b64;
        // sum the rounded values (numerator-consistent denominator).
        float rs = 0.0f;
        #pragma unroll
        for (int ct = 0; ct < 4; ++ct) {
            bf16x4 pb;
            #pragma unroll
            for (int i = 0; i < 4; ++i) {
                const bf16 p = (bf16)__builtin_amdgcn_exp2f(e[ct][i] - mnew);
                pb[i] = p;
                rs += (float)p;
            }
            *(bf16x4*)&Ps[w * 16 + l15][ct * 16 + quad * 4] = pb;
        }
        rs += __shfl_xor(rs, 16);
        rs += __shfl_xor(rs, 32);
        l_r = l_r * alpha + rs;

        // Broadcast alpha into O-row layout (O row = w*16 + quad*4 + i; alpha
        // for that row lives at lane l15' = quad*4+i, uniform across quads).
        float aO[4];
        #pragma unroll
        for (int i = 0; i < 4; ++i)
            aO[i] = __shfl(alpha, quad * 4 + i, 16);
        #pragma unroll
        for (int ct = 0; ct < 4; ++ct)
            #pragma unroll
            for (int i = 0; i < 4; ++i)
                O[ct][i] *= aO[i];

        // O += P V  (A-frags from Ps rows this wave wrote itself; no barrier
        // needed — same-wave LDS RAW handled by lgkmcnt.)
        #pragma unroll
        for (int ks = 0; ks < 64; ks += 32) {
            bf16x8 paf = *(const bf16x8*)&Ps[w * 16 + l15][ks + quad * 8];
            #pragma unroll
            for (int ct = 0; ct < 4; ++ct) {
                bf16x8 vf = *(const bf16x8*)&Vts[ct * 16 + l15][ks + quad * 8];
                O[ct] = __builtin_amdgcn_mfma_f32_16x16x32_bf16(paf, vf, O[ct], 0, 0, 0);
            }
        }
        __syncthreads();  // protect Ks/Vts before next chunk's staging
    }

    // Final normalize: l for O-row layout via the same broadcast.
    float lO[4];
    #pragma unroll
    for (int i = 0; i < 4; ++i)
        lO[i] = 1.0f / __shfl(l_r, quad * 4 + i, 16);
    #pragma unroll
    for (int ct = 0; ct < 4; ++ct)
        #pragma unroll
        for (int i = 0; i < 4; ++i) {
            const int row = q0 + w * 16 + quad * 4 + i;
            const int col = h * HDn + ct * 16 + l15;
            att[((size_t)b * Sn + row) * Dn + col] = (bf16)(O[ct][i] * lO[i]);
        }
}

// ---------------------------------------------------------------------------
// Launch
// ---------------------------------------------------------------------------
extern "C" void kernel_launch(void* const* d_in, const int* in_sizes, int n_in,
                              void* d_out, int out_size, void* d_ws, size_t ws_size,
                              hipStream_t stream) {
    const float* x   = (const float*)d_in[0];
    const int*   kpm = (const int*)d_in[1];
    const float* mod = (const float*)d_in[2];
    const float* Wq  = (const float*)d_in[3];
    const float* bq  = (const float*)d_in[4];
    const float* Wk  = (const float*)d_in[5];
    const float* bk  = (const float*)d_in[6];
    const float* Wv  = (const float*)d_in[7];
    const float* bv  = (const float*)d_in[8];
    const float* Wo  = (const float*)d_in[9];
    const float* bo  = (const float*)d_in[10];
    float* out = (float*)d_out;

    // Workspace (all bf16): xb, qb, kb, vtb, attb (8.4M each) + 4 Wt (1M each)
    bf16* ws = (bf16*)d_ws;
    const size_t sz = (size_t)Bn * Sn * Dn;   // 8388608
    const size_t wz = (size_t)Dn * Dn;        // 1048576
    bf16* xb   = ws;
    bf16* qb   = ws + sz;
    bf16* kb   = ws + 2 * sz;
    bf16* vtb  = ws + 3 * sz;
    bf16* attb = ws + 4 * sz;
    bf16* wqt  = ws + 5 * sz;
    bf16* wkt  = wqt + wz;
    bf16* wvt  = wkt + wz;
    bf16* wot  = wvt + wz;

    conv_f32_bf16_k<<<(int)(sz / 1024), 256, 0, stream>>>(x, xb, (int)sz);
    conv_wt_k<<<dim3(16, 16, 4), 256, 0, stream>>>(Wq, Wk, Wv, Wo, wqt, wkt, wvt, wot);

    const dim3 gemm_grid(128, 16);
    gemm_bf16_k<1><<<gemm_grid, 256, 0, stream>>>(xb, wqt, bq, qb);
    gemm_bf16_k<1><<<gemm_grid, 256, 0, stream>>>(xb, wkt, bk, kb);
    gemm_bf16_k<2><<<gemm_grid, 256, 0, stream>>>(xb, wvt, bv, vtb);

    attn_mfma_k<<<dim3(Bn * Hn, Sn / 64), 256, 0, stream>>>(qb, kb, vtb, kpm, mod, attb);

    gemm_bf16_k<0><<<gemm_grid, 256, 0, stream>>>(attb, wot, bo, out);
}

// Round 2
// 437.374 us; speedup vs baseline: 1.6565x; 1.1066x over previous
//
#include <hip/hip_runtime.h>
#include <cstddef>

// Problem constants: B=4, S=2048, D=1024, H=16, HD=64
constexpr int Bn  = 4;
constexpr int Sn  = 2048;
constexpr int Dn  = 1024;
constexpr int Hn  = 16;
constexpr int HDn = 64;

typedef __bf16 bf16;
typedef __attribute__((ext_vector_type(8))) __bf16 bf16x8;
typedef __attribute__((ext_vector_type(4))) __bf16 bf16x4;
typedef __attribute__((ext_vector_type(4))) float  f32x4;

typedef __attribute__((address_space(1))) const void gvoid;
typedef __attribute__((address_space(3))) void lvoid;

// ---------------------------------------------------------------------------
// Elementwise fp32 -> bf16 (x staging)
// ---------------------------------------------------------------------------
__global__ __launch_bounds__(256) void conv_f32_bf16_k(
    const float* __restrict__ in, bf16* __restrict__ out, int n)
{
    int i = (blockIdx.x * 256 + threadIdx.x) * 4;
    if (i + 3 < n) {
        float4 v = *(const float4*)(in + i);
        bf16 o[4] = {(bf16)v.x, (bf16)v.y, (bf16)v.z, (bf16)v.w};
        *(ulong1*)(out + i) = *(ulong1*)o;  // 8B store
    }
}

// ---------------------------------------------------------------------------
// Weight transpose + convert: W[k][n] fp32 -> Wt[n][k] bf16. 64x64 tiles.
// ---------------------------------------------------------------------------
__global__ __launch_bounds__(256) void conv_wt_k(
    const float* __restrict__ w0, const float* __restrict__ w1,
    const float* __restrict__ w2, const float* __restrict__ w3,
    bf16* __restrict__ o0, bf16* __restrict__ o1,
    bf16* __restrict__ o2, bf16* __restrict__ o3)
{
    const float* W = (blockIdx.z == 0) ? w0 : (blockIdx.z == 1) ? w1
                   : (blockIdx.z == 2) ? w2 : w3;
    bf16* O = (blockIdx.z == 0) ? o0 : (blockIdx.z == 1) ? o1
            : (blockIdx.z == 2) ? o2 : o3;
    __shared__ float t[64][65];
    const int tid = threadIdx.x;
    const int k0 = blockIdx.x * 64;   // row of W (k-dim)
    const int n0 = blockIdx.y * 64;   // col of W (n-dim)
    #pragma unroll
    for (int p = 0; p < 16; ++p) {
        const int idx = p * 256 + tid;
        const int r = idx >> 6, c = idx & 63;
        t[r][c] = W[(size_t)(k0 + r) * Dn + n0 + c];
    }
    __syncthreads();
    #pragma unroll
    for (int p = 0; p < 16; ++p) {
        const int idx = p * 256 + tid;
        const int r = idx >> 6, c = idx & 63;   // r: n-offset, c: k-offset
        O[(size_t)(n0 + r) * Dn + k0 + c] = (bf16)t[c][r];
    }
}

// ---------------------------------------------------------------------------
// bf16 MFMA GEMM, m97 structure: out = A(8192x1024) @ Bt^T + bias,
// Bt is [N][K] bf16. 128x128 tile, BK=64, 256 thr / 4 waves (2x2 quadrants of
// 64x64), global_load_lds dwordx4 staging into linear LDS [128][64].
// MFMA 16x16x32 bf16, fragment maps as before.
// MODE 0: fp32 out [M][N]; MODE 1: bf16 [b,h,s,hd]; MODE 2: bf16 [b,h,hd,s].
// ---------------------------------------------------------------------------
template <int MODE>
__global__ __launch_bounds__(256) void gemm_bf16_k(
    const bf16* __restrict__ A, const bf16* __restrict__ Bt,
    const float* __restrict__ bias, void* __restrict__ outv)
{
    __shared__ __align__(16) bf16 As[128 * 64];
    __shared__ __align__(16) bf16 Bs[128 * 64];

    const int tid  = threadIdx.x;
    const int w    = tid >> 6;
    const int lane = tid & 63;
    const int quad = lane >> 4;
    const int l15  = lane & 15;
    const int m0   = blockIdx.x * 128;
    const int n0   = blockIdx.y * 128;
    const int wm   = w >> 1;           // wave quadrant (2x2 of 64x64)
    const int wn   = w & 1;

    // staging geometry: one wave-issue covers 8 rows (8 lanes/row, 16B/lane)
    const int srow = lane >> 3;            // 0..7 row within issue-group
    const int scol = (lane & 7) * 8;       // element col (16B per lane)

    f32x4 acc[4][4] = {};

    for (int k0 = 0; k0 < Dn; k0 += 64) {
        #pragma unroll
        for (int j = 0; j < 4; ++j) {
            const int rbase = (w * 4 + j) * 8;      // wave-uniform
            const int r = rbase + srow;
            __builtin_amdgcn_global_load_lds(
                (gvoid*)(A + (size_t)(m0 + r) * Dn + k0 + scol),
                (lvoid*)&As[rbase * 64], 16, 0, 0);
            __builtin_amdgcn_global_load_lds(
                (gvoid*)(Bt + (size_t)(n0 + r) * Dn + k0 + scol),
                (lvoid*)&Bs[rbase * 64], 16, 0, 0);
        }
        __syncthreads();   // drains vmcnt: staged data visible

        #pragma unroll
        for (int ks = 0; ks < 64; ks += 32) {
            bf16x8 af[4], bfr[4];
            #pragma unroll
            for (int fm = 0; fm < 4; ++fm)
                af[fm] = *(const bf16x8*)&As[(wm * 64 + fm * 16 + l15) * 64 + ks + quad * 8];
            #pragma unroll
            for (int fn = 0; fn < 4; ++fn)
                bfr[fn] = *(const bf16x8*)&Bs[(wn * 64 + fn * 16 + l15) * 64 + ks + quad * 8];
            #pragma unroll
            for (int fm = 0; fm < 4; ++fm)
                #pragma unroll
                for (int fn = 0; fn < 4; ++fn)
                    acc[fm][fn] = __builtin_amdgcn_mfma_f32_16x16x32_bf16(
                        af[fm], bfr[fn], acc[fm][fn], 0, 0, 0);
        }
        __syncthreads();
    }

    #pragma unroll
    for (int fn = 0; fn < 4; ++fn) {
        const int c = n0 + wn * 64 + fn * 16 + l15;
        const float bv = bias[c];
        #pragma unroll
        for (int fm = 0; fm < 4; ++fm) {
            #pragma unroll
            for (int i = 0; i < 4; ++i) {
                const int m = m0 + wm * 64 + fm * 16 + quad * 4 + i;
                const float v = acc[fm][fn][i] + bv;
                if (MODE == 0) {
                    ((float*)outv)[(size_t)m * Dn + c] = v;
                } else {
                    const int b = m >> 11, s = m & (Sn - 1);
                    const int h = c >> 6, hd = c & 63;
                    if (MODE == 1)
                        ((bf16*)outv)[(((size_t)(b * Hn + h) * Sn) + s) * HDn + hd] = (bf16)v;
                    else
                        ((bf16*)outv)[(((size_t)(b * Hn + h) * HDn) + hd) * Sn + s] = (bf16)v;
                }
            }
        }
    }
}

// ---------------------------------------------------------------------------
// LDS XOR-swizzle (element-index form): 16B chunk column ^= row&7.
// Kills the column-read bank conflicts on [64][64] bf16 tiles (128B rows).
// Valid for any access whose element col is 4-aligned (8B) or 8-aligned (16B).
// ---------------------------------------------------------------------------
__device__ __forceinline__ int sidx(int r, int c) {
    return r * 64 + (c ^ ((r & 7) << 3));
}

// ---------------------------------------------------------------------------
// Flash attention, bf16 MFMA, swapped QK^T; per-lane q-row softmax in log2
// domain. This revision adds:
//  - 1D grid, q-tile innermost  -> K/Vt and mod[b] stay L2/L3-resident
//  - T14 async-stage split: next chunk's K/V/mod global loads issued BEFORE
//    this chunk's compute; LDS writes after the barrier (latency hidden)
//  - XOR-swizzled LDS (no padding) -> bank-conflict-free column reads
// ---------------------------------------------------------------------------
__global__ __launch_bounds__(256) void attn_mfma_k(
    const bf16* __restrict__ Qb, const bf16* __restrict__ Kb,
    const bf16* __restrict__ Vtb, const int* __restrict__ kpm,
    const float* __restrict__ mod, bf16* __restrict__ att)
{
    __shared__ __align__(16) bf16 Ks[64 * 64];
    __shared__ __align__(16) bf16 Vts[64 * 64];
    __shared__ __align__(16) bf16 Ps[64 * 64];

    const int tid  = threadIdx.x;
    const int w    = tid >> 6;
    const int lane = tid & 63;
    const int quad = lane >> 4;
    const int l15  = lane & 15;
    const int blk  = blockIdx.x;
    const int bh   = blk >> 5;             // q-tile innermost: K/V reuse
    const int q0   = (blk & 31) * 64;
    const int b    = bh >> 4;
    const int h    = bh & 15;
    const size_t base = (size_t)bh * Sn * HDn;

    const int qrow = q0 + w * 16 + l15;    // this lane's softmax q-row
    const bf16x8 qf0 = *(const bf16x8*)(Qb + base + (size_t)qrow * HDn + 0  + quad * 8);
    const bf16x8 qf1 = *(const bf16x8*)(Qb + base + (size_t)qrow * HDn + 32 + quad * 8);

    const bool qm = kpm[(size_t)b * Sn + qrow] != 0;
    const float* modrow = mod + ((size_t)b * Sn + qrow) * Sn;

    constexpr float SC = 0.125f * 1.44269504088896340736f;  // log2 domain

    float m_r = -1e30f;
    float l_r = 0.0f;
    f32x4 O[4] = {};

    // staging geometry (per thread, fixed): c = p*256+tid
    int sr[2], soff[2];
    #pragma unroll
    for (int p = 0; p < 2; ++p) {
        const int c = p * 256 + tid;
        sr[p] = c >> 3; soff[p] = (c & 7) * 8;
    }

    // ---- prologue: stage chunk 0, prefetch mod chunk 0 ----
    bf16x8 kst[2], vst[2];
    float4 md[4];
    #pragma unroll
    for (int p = 0; p < 2; ++p) {
        kst[p] = *(const bf16x8*)(Kb + base + (size_t)sr[p] * HDn + soff[p]);
        vst[p] = *(const bf16x8*)(Vtb + base + (size_t)sr[p] * Sn + 0 + soff[p]);
    }
    #pragma unroll
    for (int ct = 0; ct < 4; ++ct)
        md[ct] = *(const float4*)(modrow + 0 + ct * 16 + quad * 4);
    #pragma unroll
    for (int p = 0; p < 2; ++p) {
        *(bf16x8*)&Ks[sidx(sr[p], soff[p])]  = kst[p];
        *(bf16x8*)&Vts[sidx(sr[p], soff[p])] = vst[p];
    }
    __syncthreads();

    constexpr int NT = Sn / 64;
    for (int t = 0; t < NT; ++t) {
        const int k0 = t * 64;

        // ---- issue next chunk's global loads (latency hides under compute)
        float4 mdn[4];
        if (t + 1 < NT) {
            const int kn = k0 + 64;
            #pragma unroll
            for (int p = 0; p < 2; ++p) {
                kst[p] = *(const bf16x8*)(Kb + base + (size_t)(kn + sr[p]) * HDn + soff[p]);
                vst[p] = *(const bf16x8*)(Vtb + base + (size_t)sr[p] * Sn + kn + soff[p]);
            }
            #pragma unroll
            for (int ct = 0; ct < 4; ++ct)
                mdn[ct] = *(const float4*)(modrow + kn + ct * 16 + quad * 4);
        }

        // ---- QK^T (swapped): lane holds e[k = ct*16+quad*4+i] for its q-row
        float e[4][4];
        #pragma unroll
        for (int ct = 0; ct < 4; ++ct) {
            f32x4 s = {};
            #pragma unroll
            for (int ks = 0; ks < 64; ks += 32) {
                bf16x8 kf = *(const bf16x8*)&Ks[sidx(ct * 16 + l15, ks + quad * 8)];
                s = __builtin_amdgcn_mfma_f32_16x16x32_bf16(kf, ks ? qf1 : qf0, s, 0, 0, 0);
            }
            #pragma unroll
            for (int i = 0; i < 4; ++i)
                e[ct][i] = qm ? -1e10f : s[i] * SC * (&md[ct].x)[i];
        }

        // ---- online softmax: 15 in-reg fmax + 2 cross-quad shfl
        float pmax = e[0][0];
        #pragma unroll
        for (int ct = 0; ct < 4; ++ct)
            #pragma unroll
            for (int i = 0; i < 4; ++i)
                pmax = fmaxf(pmax, e[ct][i]);
        pmax = fmaxf(pmax, __shfl_xor(pmax, 16));
        pmax = fmaxf(pmax, __shfl_xor(pmax, 32));

        const float mnew  = fmaxf(m_r, pmax);
        const float alpha = __builtin_amdgcn_exp2f(m_r - mnew);
        m_r = mnew;

        float rs = 0.0f;
        #pragma unroll
        for (int ct = 0; ct < 4; ++ct) {
            bf16x4 pb;
            #pragma unroll
            for (int i = 0; i < 4; ++i) {
                const bf16 p = (bf16)__builtin_amdgcn_exp2f(e[ct][i] - mnew);
                pb[i] = p;
                rs += (float)p;
            }
            *(bf16x4*)&Ps[sidx(w * 16 + l15, ct * 16 + quad * 4)] = pb;
        }
        rs += __shfl_xor(rs, 16);
        rs += __shfl_xor(rs, 32);
        l_r = l_r * alpha + rs;

        // alpha into O-row layout (row = quad*4+i -> lane quad*4+i of group)
        float aO[4];
        #pragma unroll
        for (int i = 0; i < 4; ++i)
            aO[i] = __shfl(alpha, quad * 4 + i, 16);
        #pragma unroll
        for (int ct = 0; ct < 4; ++ct)
            #pragma unroll
            for (int i = 0; i < 4; ++i)
                O[ct][i] *= aO[i];

        // ---- O += P V (Ps rows are wave-local; same-wave RAW via lgkmcnt)
        #pragma unroll
        for (int ks = 0; ks < 64; ks += 32) {
            bf16x8 paf = *(const bf16x8*)&Ps[sidx(w * 16 + l15, ks + quad * 8)];
            #pragma unroll
            for (int ct = 0; ct < 4; ++ct) {
                bf16x8 vf = *(const bf16x8*)&Vts[sidx(ct * 16 + l15, ks + quad * 8)];
                O[ct] = __builtin_amdgcn_mfma_f32_16x16x32_bf16(paf, vf, O[ct], 0, 0, 0);
            }
        }

        __syncthreads();   // all waves done reading Ks/Vts[t]
        if (t + 1 < NT) {
            #pragma unroll
            for (int p = 0; p < 2; ++p) {
                *(bf16x8*)&Ks[sidx(sr[p], soff[p])]  = kst[p];
                *(bf16x8*)&Vts[sidx(sr[p], soff[p])] = vst[p];
            }
            #pragma unroll
            for (int ct = 0; ct < 4; ++ct)
                md[ct] = mdn[ct];
        }
        __syncthreads();   // staged chunk t+1 visible
    }

    float lO[4];
    #pragma unroll
    for (int i = 0; i < 4; ++i)
        lO[i] = 1.0f / __shfl(l_r, quad * 4 + i, 16);
    #pragma unroll
    for (int ct = 0; ct < 4; ++ct)
        #pragma unroll
        for (int i = 0; i < 4; ++i) {
            const int row = q0 + w * 16 + quad * 4 + i;
            const int col = h * HDn + ct * 16 + l15;
            att[((size_t)b * Sn + row) * Dn + col] = (bf16)(O[ct][i] * lO[i]);
        }
}

// ---------------------------------------------------------------------------
// Launch
// ---------------------------------------------------------------------------
extern "C" void kernel_launch(void* const* d_in, const int* in_sizes, int n_in,
                              void* d_out, int out_size, void* d_ws, size_t ws_size,
                              hipStream_t stream) {
    const float* x   = (const float*)d_in[0];
    const int*   kpm = (const int*)d_in[1];
    const float* mod = (const float*)d_in[2];
    const float* Wq  = (const float*)d_in[3];
    const float* bq  = (const float*)d_in[4];
    const float* Wk  = (const float*)d_in[5];
    const float* bk  = (const float*)d_in[6];
    const float* Wv  = (const float*)d_in[7];
    const float* bv  = (const float*)d_in[8];
    const float* Wo  = (const float*)d_in[9];
    const float* bo  = (const float*)d_in[10];
    float* out = (float*)d_out;

    // Workspace (all bf16): xb, qb, kb, vtb, attb (8.4M each) + 4 Wt (1M each)
    bf16* ws = (bf16*)d_ws;
    const size_t sz = (size_t)Bn * Sn * Dn;   // 8388608
    const size_t wz = (size_t)Dn * Dn;        // 1048576
    bf16* xb   = ws;
    bf16* qb   = ws + sz;
    bf16* kb   = ws + 2 * sz;
    bf16* vtb  = ws + 3 * sz;
    bf16* attb = ws + 4 * sz;
    bf16* wqt  = ws + 5 * sz;
    bf16* wkt  = wqt + wz;
    bf16* wvt  = wkt + wz;
    bf16* wot  = wvt + wz;

    conv_f32_bf16_k<<<(int)(sz / 1024), 256, 0, stream>>>(x, xb, (int)sz);
    conv_wt_k<<<dim3(16, 16, 4), 256, 0, stream>>>(Wq, Wk, Wv, Wo, wqt, wkt, wvt, wot);

    const dim3 gemm_grid(64, 8);   // 128x128 tiles over 8192x1024
    gemm_bf16_k<1><<<gemm_grid, 256, 0, stream>>>(xb, wqt, bq, qb);
    gemm_bf16_k<1><<<gemm_grid, 256, 0, stream>>>(xb, wkt, bk, kb);
    gemm_bf16_k<2><<<gemm_grid, 256, 0, stream>>>(xb, wvt, bv, vtb);

    attn_mfma_k<<<Bn * Hn * (Sn / 64), 256, 0, stream>>>(qb, kb, vtb, kpm, mod, attb);

    gemm_bf16_k<0><<<gemm_grid, 256, 0, stream>>>(attb, wot, bo, out);
}